// Round 1
// baseline (564.203 us; speedup 1.0000x reference)
//
#include <hip/hip_runtime.h>
#include <cfloat>

namespace {
constexpr int kHW = 4096;   // 64*64 spatial
constexpr int kC = 64;      // channels == code dim
constexpr int kK = 1024;    // codes
constexpr float kInvN = 1.0f / 65536.0f;

// ---------------- prep: w = -2c, bias = ||c||^2, zero accumulators ----------
__global__ __launch_bounds__(64) void prep_kernel(
    const float* __restrict__ cb, float* __restrict__ wmat,
    float* __restrict__ bias, unsigned int* __restrict__ hist,
    float* __restrict__ lossacc) {
  int k = blockIdx.x;
  int d = threadIdx.x;
  float c = cb[k * kC + d];
  wmat[k * kC + d] = -2.0f * c;
  float s = c * c;
  #pragma unroll
  for (int off = 32; off; off >>= 1) s += __shfl_xor(s, off, 64);
  if (d == 0) {
    bias[k] = s;
    hist[k] = 0u;
    if (k == 0) lossacc[0] = 0.0f;
  }
}

// ---------------- argmin over codes ----------------------------------------
// Block = 256 threads = 4 waves. Each block owns 64 columns (spatial sites);
// wave w scans code chunk [w*256, w*256+256). x kept in 64 VGPRs; codebook
// row accesses are wave-uniform -> scalar loads (SGPR operand FMAs).
__global__ __launch_bounds__(256) void argmin_kernel(
    const float* __restrict__ in, const float* __restrict__ wmat,
    const float* __restrict__ bias, unsigned int* __restrict__ idx,
    unsigned int* __restrict__ hist) {
  const int t = threadIdx.x;
  const int wv = t >> 6;
  const int l = t & 63;
  const int col = blockIdx.x * 64 + l;
  const int batch = col >> 12;   // 4096 columns per batch image
  const int hw = col & 4095;
  const float* xp = in + batch * (kC * kHW) + hw;
  float x[kC];
  #pragma unroll
  for (int d = 0; d < kC; ++d) x[d] = xp[d * kHW];

  float best = FLT_MAX;
  int bi = 0;
  const int k0 = wv * 256;
  #pragma unroll 1
  for (int k = k0; k < k0 + 256; ++k) {
    const float* wk = wmat + (k << 6);       // uniform -> s_load
    float p0 = bias[k], p1 = 0.f, p2 = 0.f, p3 = 0.f;
    #pragma unroll
    for (int d = 0; d < kC; d += 4) {
      p0 = fmaf(wk[d + 0], x[d + 0], p0);
      p1 = fmaf(wk[d + 1], x[d + 1], p1);
      p2 = fmaf(wk[d + 2], x[d + 2], p2);
      p3 = fmaf(wk[d + 3], x[d + 3], p3);
    }
    float dist = (p0 + p1) + (p2 + p3);      // ||c||^2 - 2 x.c
    if (dist < best) { best = dist; bi = k; }   // strict < keeps first k on ties
  }

  __shared__ float sd[4][64];
  __shared__ int si[4][64];
  sd[wv][l] = best;
  si[wv][l] = bi;
  __syncthreads();
  if (wv == 0) {
    #pragma unroll
    for (int w2 = 1; w2 < 4; ++w2) {          // ascending chunk -> first-k ties
      float d2 = sd[w2][l];
      int i2 = si[w2][l];
      if (d2 < best) { best = d2; bi = i2; }
    }
    idx[col] = (unsigned int)bi;
    atomicAdd(&hist[bi], 1u);
  }
}

// ---------------- gather + transpose write + loss --------------------------
__global__ __launch_bounds__(256) void gather_kernel(
    const float* __restrict__ in, const float* __restrict__ cb,
    const unsigned int* __restrict__ idx, float* __restrict__ qout,
    float* __restrict__ lossacc) {
  const int n = blockIdx.x * 256 + threadIdx.x;
  const int batch = n >> 12;
  const int hw = n & 4095;
  const float* q = cb + idx[n] * kC;
  const float* xp = in + batch * (kC * kHW) + hw;
  float* op = qout + batch * (kC * kHW) + hw;
  float qv[kC];
  #pragma unroll
  for (int d = 0; d < kC; d += 4) {
    float4 v = *reinterpret_cast<const float4*>(q + d);
    qv[d] = v.x; qv[d + 1] = v.y; qv[d + 2] = v.z; qv[d + 3] = v.w;
  }
  float s = 0.0f;
  #pragma unroll
  for (int d = 0; d < kC; ++d) {
    float xv = xp[d * kHW];
    float diff = qv[d] - xv;                 // q - x
    s = fmaf(diff, diff, s);
    op[d * kHW] = xv + diff;                 // x + (q - x): straight-through
  }
  #pragma unroll
  for (int off = 32; off; off >>= 1) s += __shfl_xor(s, off, 64);
  if ((threadIdx.x & 63) == 0) atomicAdd(lossacc, s);
}

// ---------------- finalize: loss scalar + perplexity -----------------------
__global__ __launch_bounds__(1024) void finalize_kernel(
    const unsigned int* __restrict__ hist, const float* __restrict__ lossacc,
    const float* __restrict__ beta, float* __restrict__ out) {
  __shared__ float red[16];
  const int t = threadIdx.x;
  float e = (float)hist[t] * kInvN;
  float term = e * logf(e + 1e-10f);
  #pragma unroll
  for (int off = 32; off; off >>= 1) term += __shfl_xor(term, off, 64);
  if ((t & 63) == 0) red[t >> 6] = term;
  __syncthreads();
  if (t == 0) {
    float h = 0.0f;
    #pragma unroll
    for (int i = 0; i < 16; ++i) h += red[i];
    out[1 + 4194304] = expf(-h);                                  // perplexity
    out[0] = lossacc[0] * (1.0f + beta[0]) * 10.0f / 4194304.0f;  // loss
  }
}
}  // namespace

extern "C" void kernel_launch(void* const* d_in, const int* in_sizes, int n_in,
                              void* d_out, int out_size, void* d_ws, size_t ws_size,
                              hipStream_t stream) {
  const float* inputs = (const float*)d_in[0];   // [16,64,64,64] fp32
  const float* cb = (const float*)d_in[1];       // [1024,64] fp32
  const float* beta = (const float*)d_in[2];     // scalar
  float* out = (float*)d_out;                    // [1 + 4194304 + 1]
  float* ws = (float*)d_ws;

  float* wmat = ws;                                   // 65536 f
  float* bias = ws + 65536;                           // 1024 f
  unsigned int* hist = (unsigned int*)(ws + 66560);   // 1024 u32
  float* lossacc = ws + 67584;                        // 1 f
  unsigned int* idx = (unsigned int*)(ws + 67648);    // 65536 u32

  prep_kernel<<<1024, 64, 0, stream>>>(cb, wmat, bias, hist, lossacc);
  argmin_kernel<<<1024, 256, 0, stream>>>(inputs, wmat, bias, idx, hist);
  gather_kernel<<<256, 256, 0, stream>>>(inputs, cb, idx, out + 1, lossacc);
  finalize_kernel<<<1, 1024, 0, stream>>>(hist, lossacc, beta, out);
}

// Round 2
// 221.095 us; speedup vs baseline: 2.5519x; 2.5519x over previous
//
#include <hip/hip_runtime.h>
#include <cfloat>

namespace {
constexpr int kHW = 4096;   // 64*64 spatial per image
constexpr int kC = 64;      // channels == code dim
constexpr int kK = 1024;    // codes
constexpr float kInvN = 1.0f / 65536.0f;

// ---------------- prep: bias = ||c||^2, zero accumulators -------------------
__global__ __launch_bounds__(64) void prep_kernel(
    const float* __restrict__ cb, float* __restrict__ bias,
    unsigned int* __restrict__ hist, float* __restrict__ lossacc) {
  int k = blockIdx.x;
  int d = threadIdx.x;
  float c = cb[k * kC + d];
  float s = c * c;
  #pragma unroll
  for (int off = 32; off; off >>= 1) s += __shfl_xor(s, off, 64);
  if (d == 0) {
    bias[k] = s;
    hist[k] = 0u;
    if (k == 0) lossacc[0] = 0.0f;
  }
}

// ---------------- fused: argmin GEMM + quantized output + loss --------------
// Block: 256 thr (4 waves), owns 64 sites (one hw0..hw0+63 strip of one image).
// Register tile: 4 sites x 4 codes per thread; 16 FMA per 2 ds_read_b128.
// W chunks of 64 codes staged transposed [d][k] in LDS, double-buffered.
__global__ __launch_bounds__(256) void vq_kernel(
    const float* __restrict__ in, const float* __restrict__ cb,
    const float* __restrict__ bias, unsigned int* __restrict__ hist,
    float* __restrict__ lossacc, float* __restrict__ qout) {
  __shared__ __align__(16) char smem[49152];
  float (*sX)[64] = reinterpret_cast<float (*)[64]>(smem);                  // [64 d][64 s] 16KB
  float (*sW)[64][64] = reinterpret_cast<float (*)[64][64]>(smem + 16384);  // [2][d][k] 32KB
  // reuse of the sW region after the compute loop's final barrier:
  float (*sRedD)[17] = reinterpret_cast<float (*)[17]>(smem + 16384);       // [64 s][17]
  int (*sRedI)[17] = reinterpret_cast<int (*)[17]>(smem + 16384 + 4352);    // [64 s][17]
  int* sIdx = reinterpret_cast<int*>(smem + 16384 + 8704);                  // [64]

  const int t = threadIdx.x;
  const int lane = t & 63;
  const int wv = t >> 6;
  const int b = blockIdx.x >> 6;
  const int hw0 = (blockIdx.x & 63) << 6;
  const float* xin = in + b * (kC * kHW) + hw0;

  // --- stage X tile [d][s] (once): coalesced float4 along s ---
  {
    const int sq = (lane & 15) << 2;       // s offset
    const int dr = (wv << 4) + (lane >> 4);
    #pragma unroll
    for (int i = 0; i < 4; ++i) {
      const int d = dr + (i << 2);
      float4 v = *reinterpret_cast<const float4*>(xin + d * kHW + sq);
      *reinterpret_cast<float4*>(&sX[d][sq]) = v;
    }
  }

  // --- stage W chunk 0 transposed: thread t covers code kl, dims dgq*16.. ---
  const int kl = t & 63;
  const int dgq = t >> 6;
  {
    const float* crow = cb + kl * kC + (dgq << 4);
    #pragma unroll
    for (int i = 0; i < 4; ++i) {
      float4 v = *reinterpret_cast<const float4*>(crow + (i << 2));
      const int d = (dgq << 4) + (i << 2);
      sW[0][d + 0][kl] = v.x;   // lanes contiguous in kl -> conflict-free
      sW[0][d + 1][kl] = v.y;
      sW[0][d + 2][kl] = v.z;
      sW[0][d + 3][kl] = v.w;
    }
  }
  __syncthreads();

  const int sg = t >> 4;   // site group: sites sg*4 .. +3
  const int cg = t & 15;   // code group: codes cg*4 .. +3 within chunk
  float best[4] = {FLT_MAX, FLT_MAX, FLT_MAX, FLT_MAX};
  int bidx[4] = {0, 0, 0, 0};
  int buf = 0;

  for (int chunk = 0; chunk < 16; ++chunk) {
    // T14 async-stage split: issue next chunk's global loads now...
    float4 n0, n1, n2, n3;
    if (chunk < 15) {
      const float* crow = cb + (((chunk + 1) << 6) + kl) * kC + (dgq << 4);
      n0 = *reinterpret_cast<const float4*>(crow + 0);
      n1 = *reinterpret_cast<const float4*>(crow + 4);
      n2 = *reinterpret_cast<const float4*>(crow + 8);
      n3 = *reinterpret_cast<const float4*>(crow + 12);
    }

    float acc[4][4] = {{0.f, 0.f, 0.f, 0.f}, {0.f, 0.f, 0.f, 0.f},
                       {0.f, 0.f, 0.f, 0.f}, {0.f, 0.f, 0.f, 0.f}};
    #pragma unroll 16
    for (int d = 0; d < 64; ++d) {
      float4 xa = *reinterpret_cast<const float4*>(&sX[d][sg << 2]);
      float4 wb = *reinterpret_cast<const float4*>(&sW[buf][d][cg << 2]);
      acc[0][0] = fmaf(xa.x, wb.x, acc[0][0]);
      acc[0][1] = fmaf(xa.x, wb.y, acc[0][1]);
      acc[0][2] = fmaf(xa.x, wb.z, acc[0][2]);
      acc[0][3] = fmaf(xa.x, wb.w, acc[0][3]);
      acc[1][0] = fmaf(xa.y, wb.x, acc[1][0]);
      acc[1][1] = fmaf(xa.y, wb.y, acc[1][1]);
      acc[1][2] = fmaf(xa.y, wb.z, acc[1][2]);
      acc[1][3] = fmaf(xa.y, wb.w, acc[1][3]);
      acc[2][0] = fmaf(xa.z, wb.x, acc[2][0]);
      acc[2][1] = fmaf(xa.z, wb.y, acc[2][1]);
      acc[2][2] = fmaf(xa.z, wb.z, acc[2][2]);
      acc[2][3] = fmaf(xa.z, wb.w, acc[2][3]);
      acc[3][0] = fmaf(xa.w, wb.x, acc[3][0]);
      acc[3][1] = fmaf(xa.w, wb.y, acc[3][1]);
      acc[3][2] = fmaf(xa.w, wb.z, acc[3][2]);
      acc[3][3] = fmaf(xa.w, wb.w, acc[3][3]);
    }

    // dist = ||c||^2 - 2 x.c ; update running argmin (codes ascending)
    const int kbase = (chunk << 6) + (cg << 2);
    float4 bv = *reinterpret_cast<const float4*>(bias + kbase);
    #pragma unroll
    for (int i = 0; i < 4; ++i) {
      float d0 = fmaf(acc[i][0], -2.0f, bv.x);
      float d1 = fmaf(acc[i][1], -2.0f, bv.y);
      float d2 = fmaf(acc[i][2], -2.0f, bv.z);
      float d3 = fmaf(acc[i][3], -2.0f, bv.w);
      if (d0 < best[i]) { best[i] = d0; bidx[i] = kbase; }
      if (d1 < best[i]) { best[i] = d1; bidx[i] = kbase + 1; }
      if (d2 < best[i]) { best[i] = d2; bidx[i] = kbase + 2; }
      if (d3 < best[i]) { best[i] = d3; bidx[i] = kbase + 3; }
    }

    // ...write staged regs to the other buffer after compute (latency hidden)
    if (chunk < 15) {
      const int d = dgq << 4;
      float vv[16] = {n0.x, n0.y, n0.z, n0.w, n1.x, n1.y, n1.z, n1.w,
                      n2.x, n2.y, n2.z, n2.w, n3.x, n3.y, n3.z, n3.w};
      #pragma unroll
      for (int j = 0; j < 16; ++j) sW[buf ^ 1][d + j][kl] = vv[j];
    }
    __syncthreads();
    buf ^= 1;
  }

  // --- cross-thread argmin reduce (16 code-groups per site) ---
  #pragma unroll
  for (int i = 0; i < 4; ++i) {
    sRedD[(sg << 2) + i][cg] = best[i];
    sRedI[(sg << 2) + i][cg] = bidx[i];
  }
  __syncthreads();
  if (t < 64) {
    float bb = FLT_MAX;
    int bi = 0x7fffffff;
    #pragma unroll
    for (int c2 = 0; c2 < 16; ++c2) {
      float d2 = sRedD[t][c2];
      int i2 = sRedI[t][c2];
      if (d2 < bb || (d2 == bb && i2 < bi)) { bb = d2; bi = i2; }
    }
    sIdx[t] = bi;
    atomicAdd(&hist[bi], 1u);
  }
  __syncthreads();

  // --- output: quantized = x + (q - x), fused loss sum ---
  {
    const int s = lane;
    const int row = sIdx[s];
    const float* qrow = cb + row * kC + (wv << 4);
    float* op = qout + b * (kC * kHW) + hw0 + s;
    float ls = 0.0f;
    #pragma unroll
    for (int i = 0; i < 4; ++i) {
      float4 qv = *reinterpret_cast<const float4*>(qrow + (i << 2));
      const int d = (wv << 4) + (i << 2);
      float q[4] = {qv.x, qv.y, qv.z, qv.w};
      #pragma unroll
      for (int j = 0; j < 4; ++j) {
        float xv = sX[d + j][s];
        float diff = q[j] - xv;               // q - x
        ls = fmaf(diff, diff, ls);
        op[(d + j) * kHW] = xv + diff;        // straight-through: x + (q-x)
      }
    }
    #pragma unroll
    for (int off = 32; off; off >>= 1) ls += __shfl_xor(ls, off, 64);
    if (lane == 0) atomicAdd(lossacc, ls);
  }
}

// ---------------- finalize: loss scalar + perplexity ------------------------
__global__ __launch_bounds__(1024) void finalize_kernel(
    const unsigned int* __restrict__ hist, const float* __restrict__ lossacc,
    const float* __restrict__ beta, float* __restrict__ out) {
  __shared__ float red[16];
  const int t = threadIdx.x;
  float e = (float)hist[t] * kInvN;
  float term = e * logf(e + 1e-10f);
  #pragma unroll
  for (int off = 32; off; off >>= 1) term += __shfl_xor(term, off, 64);
  if ((t & 63) == 0) red[t >> 6] = term;
  __syncthreads();
  if (t == 0) {
    float h = 0.0f;
    #pragma unroll
    for (int i = 0; i < 16; ++i) h += red[i];
    out[1 + 4194304] = expf(-h);                                  // perplexity
    out[0] = lossacc[0] * (1.0f + beta[0]) * 10.0f / 4194304.0f;  // loss
  }
}
}  // namespace

extern "C" void kernel_launch(void* const* d_in, const int* in_sizes, int n_in,
                              void* d_out, int out_size, void* d_ws, size_t ws_size,
                              hipStream_t stream) {
  const float* inputs = (const float*)d_in[0];   // [16,64,64,64] fp32
  const float* cb = (const float*)d_in[1];       // [1024,64] fp32
  const float* beta = (const float*)d_in[2];     // scalar
  float* out = (float*)d_out;                    // [1 + 4194304 + 1]
  float* ws = (float*)d_ws;

  float* bias = ws;                                  // 1024 f
  unsigned int* hist = (unsigned int*)(ws + 1024);   // 1024 u32
  float* lossacc = ws + 2048;                        // 1 f

  prep_kernel<<<1024, 64, 0, stream>>>(cb, bias, hist, lossacc);
  vq_kernel<<<1024, 256, 0, stream>>>(inputs, cb, bias, hist, lossacc, out + 1);
  finalize_kernel<<<1, 1024, 0, stream>>>(hist, lossacc, beta, out);
}

// Round 3
// 127.504 us; speedup vs baseline: 4.4250x; 1.7340x over previous
//
#include <hip/hip_runtime.h>
#include <cfloat>

typedef __bf16 bf16x8 __attribute__((ext_vector_type(8)));
typedef float f32x16 __attribute__((ext_vector_type(16)));

namespace {
constexpr int kHW = 4096;     // 64*64 spatial per image
constexpr int kC = 64;        // channels == code dim
constexpr float kInvN = 1.0f / 65536.0f;

// ws layout (bytes): [0, 294912): A-frags (32 chunks * 9 slots * 64 lanes * 16B)
//                    [294912, +4096): hist (1024 u32)   [+4096, +4): lossacc
// Frag slot order per chunk: 0..3 = Ah(ks), 4..7 = Al(ks), 8 = bias.

// ---------------- prep: build -2*C bf16-split fragments + bias frag ---------
__global__ __launch_bounds__(64) void prep_kernel(
    const float* __restrict__ cb, uint4* __restrict__ frags,
    unsigned int* __restrict__ hist, float* __restrict__ lossacc) {
  const int c = blockIdx.x;        // chunk of 32 codes
  const int l = threadIdx.x;       // lane position within fragment
  const int lo = l & 31, hi = l >> 5;
  const int code = c * 32 + lo;

  #pragma unroll
  for (int ks = 0; ks < 4; ++ks) {
    bf16x8 fh, fl;
    #pragma unroll
    for (int e = 0; e < 8; ++e) {
      const int d = ks * 16 + hi * 8 + e;
      float v = -2.0f * cb[code * kC + d];
      __bf16 h = (__bf16)v;
      fh[e] = h;
      fl[e] = (__bf16)(v - (float)h);
    }
    frags[(c * 9 + ks) * 64 + l] = *reinterpret_cast<uint4*>(&fh);
    frags[(c * 9 + 4 + ks) * 64 + l] = *reinterpret_cast<uint4*>(&fl);
  }
  // bias frag: k-slot 0 = bias_h, 1 = bias_l (only lane-half 0 carries k=0..7)
  bf16x8 fb;
  #pragma unroll
  for (int e = 0; e < 8; ++e) fb[e] = (__bf16)0.0f;
  if (hi == 0) {
    float s = 0.0f;
    #pragma unroll
    for (int d = 0; d < kC; d += 4) {
      float4 v = *reinterpret_cast<const float4*>(cb + code * kC + d);
      s = fmaf(v.x, v.x, fmaf(v.y, v.y, fmaf(v.z, v.z, fmaf(v.w, v.w, s))));
    }
    __bf16 h = (__bf16)s;
    fb[0] = h;
    fb[1] = (__bf16)(s - (float)h);
    hist[code] = 0u;
  }
  frags[(c * 9 + 8) * 64 + l] = *reinterpret_cast<uint4*>(&fb);
  if (c == 0 && l == 0) lossacc[0] = 0.0f;
}

// ---------------- fused: MFMA argmin + output + loss ------------------------
// Block = 4 waves, wave owns 32 sites (B-operand cols). 32 chunks of 32 codes
// (A-operand rows) streamed from L2 with 2-deep register double-buffer.
__global__ __launch_bounds__(256) void vq_kernel(
    const float* __restrict__ in, const bf16x8* __restrict__ frags,
    const float* __restrict__ cb, unsigned int* __restrict__ hist,
    float* __restrict__ lossacc, float* __restrict__ qout) {
  __shared__ int sIdx[128];
  const int t = threadIdx.x;
  const int lane = t & 63, wv = t >> 6;
  const int lo = lane & 31, hi = lane >> 5;
  const int site = blockIdx.x * 128 + wv * 32 + lo;
  const int b = site >> 12, hw = site & 4095;
  const float* xp = in + b * (kC * kHW) + hw;

  // --- X fragments: bf16 hi/lo split, 8 consecutive d per lane-half ---
  bf16x8 Bh[4], Bl[4];
  #pragma unroll
  for (int ks = 0; ks < 4; ++ks) {
    #pragma unroll
    for (int e = 0; e < 8; ++e) {
      const int d = ks * 16 + hi * 8 + e;
      float v = xp[d * kHW];
      __bf16 h = (__bf16)v;
      Bh[ks][e] = h;
      Bl[ks][e] = (__bf16)(v - (float)h);
    }
  }
  bf16x8 ones;
  #pragma unroll
  for (int e = 0; e < 8; ++e) ones[e] = (__bf16)0.0f;
  if (hi == 0) { ones[0] = (__bf16)1.0f; ones[1] = (__bf16)1.0f; }
  f32x16 zero;
  #pragma unroll
  for (int r = 0; r < 16; ++r) zero[r] = 0.0f;

  float best[16];
  int bch[16];
  #pragma unroll
  for (int r = 0; r < 16; ++r) { best[r] = FLT_MAX; bch[r] = 0; }

  const bf16x8* fA = frags + lane;   // entry j of chunk c at fA[(c*9+j)*64]

  bf16x8 A0[9], A1[9];
  auto prefetch = [&](bf16x8(&F)[9], int c) {
    #pragma unroll
    for (int j = 0; j < 9; ++j) F[j] = fA[(c * 9 + j) * 64];
  };
  auto compute = [&](const bf16x8(&F)[9], int c) {
    // dist = bias + (-2c).x via 3-pass bf16 split; two acc chains for ILP
    f32x16 a1 = __builtin_amdgcn_mfma_f32_32x32x16_bf16(F[8], ones, zero, 0, 0, 0);
    f32x16 a2 = zero;
    #pragma unroll
    for (int ks = 0; ks < 4; ++ks) {
      a1 = __builtin_amdgcn_mfma_f32_32x32x16_bf16(F[ks], Bh[ks], a1, 0, 0, 0);
      a2 = __builtin_amdgcn_mfma_f32_32x32x16_bf16(F[4 + ks], Bh[ks], a2, 0, 0, 0);
      a2 = __builtin_amdgcn_mfma_f32_32x32x16_bf16(F[ks], Bl[ks], a2, 0, 0, 0);
    }
    #pragma unroll
    for (int r = 0; r < 16; ++r) {
      float d = a1[r] + a2[r];
      bool p = d < best[r];            // strict < : earliest chunk wins ties
      best[r] = p ? d : best[r];
      bch[r] = p ? c : bch[r];
    }
  };

  prefetch(A0, 0);
  #pragma unroll 1
  for (int c = 0; c < 32; c += 2) {
    prefetch(A1, c + 1);
    compute(A0, c);
    if (c + 2 < 32) prefetch(A0, c + 2);
    compute(A1, c + 1);
  }

  // --- per-lane (val, idx) reduce over 16 acc rows, then half-merge ---
  float bv = best[0];
  int bidx = bch[0] * 32 + (hi << 2);       // kloc(r=0) = 0 + 4*hi
  #pragma unroll
  for (int r = 1; r < 16; ++r) {
    const int kloc = (r & 3) + 8 * (r >> 2) + (hi << 2);
    int idx = bch[r] * 32 + kloc;
    float v = best[r];
    if (v < bv || (v == bv && idx < bidx)) { bv = v; bidx = idx; }
  }
  float ov = __shfl_xor(bv, 32, 64);
  int oi = __shfl_xor(bidx, 32, 64);
  if (ov < bv || (ov == bv && oi < bidx)) { bv = ov; bidx = oi; }
  if (hi == 0) {
    sIdx[wv * 32 + lo] = bidx;
    atomicAdd(&hist[bidx], 1u);
  }
  __syncthreads();

  // --- output: quantized = x + (q - x), fused loss ---
  {
    const int s2 = t & 127;
    const int dbase = (t >> 7) * 32;
    const int gsite = blockIdx.x * 128 + s2;
    const int b2 = gsite >> 12, hw2 = gsite & 4095;
    const int code = sIdx[s2];
    const float* xr = in + b2 * (kC * kHW) + hw2;
    const float* qr = cb + code * kC + dbase;
    float* op = qout + b2 * (kC * kHW) + hw2;
    float ls = 0.0f;
    #pragma unroll
    for (int j = 0; j < 32; j += 4) {
      float4 qv = *reinterpret_cast<const float4*>(qr + j);
      float q[4] = {qv.x, qv.y, qv.z, qv.w};
      #pragma unroll
      for (int u = 0; u < 4; ++u) {
        const int d = dbase + j + u;
        float xv = xr[d * kHW];
        float diff = q[u] - xv;              // q - x
        ls = fmaf(diff, diff, ls);
        op[d * kHW] = xv + diff;             // straight-through: x + (q-x)
      }
    }
    #pragma unroll
    for (int off = 32; off; off >>= 1) ls += __shfl_xor(ls, off, 64);
    if (lane == 0) atomicAdd(lossacc, ls);
  }
}

// ---------------- finalize: loss scalar + perplexity ------------------------
__global__ __launch_bounds__(1024) void finalize_kernel(
    const unsigned int* __restrict__ hist, const float* __restrict__ lossacc,
    const float* __restrict__ beta, float* __restrict__ out) {
  __shared__ float red[16];
  const int t = threadIdx.x;
  float e = (float)hist[t] * kInvN;
  float term = e * logf(e + 1e-10f);
  #pragma unroll
  for (int off = 32; off; off >>= 1) term += __shfl_xor(term, off, 64);
  if ((t & 63) == 0) red[t >> 6] = term;
  __syncthreads();
  if (t == 0) {
    float h = 0.0f;
    #pragma unroll
    for (int i = 0; i < 16; ++i) h += red[i];
    out[1 + 4194304] = expf(-h);                                  // perplexity
    out[0] = lossacc[0] * (1.0f + beta[0]) * 10.0f / 4194304.0f;  // loss
  }
}
}  // namespace

extern "C" void kernel_launch(void* const* d_in, const int* in_sizes, int n_in,
                              void* d_out, int out_size, void* d_ws, size_t ws_size,
                              hipStream_t stream) {
  const float* inputs = (const float*)d_in[0];   // [16,64,64,64] fp32
  const float* cb = (const float*)d_in[1];       // [1024,64] fp32
  const float* beta = (const float*)d_in[2];     // scalar
  float* out = (float*)d_out;                    // [1 + 4194304 + 1]

  uint4* frags = (uint4*)d_ws;                                        // 294912 B
  unsigned int* hist = (unsigned int*)((char*)d_ws + 294912);         // 4 KB
  float* lossacc = (float*)((char*)d_ws + 294912 + 4096);             // 4 B

  prep_kernel<<<32, 64, 0, stream>>>(cb, frags, hist, lossacc);
  vq_kernel<<<512, 256, 0, stream>>>(inputs, (const bf16x8*)frags, cb, hist,
                                     lossacc, out + 1);
  finalize_kernel<<<1, 1024, 0, stream>>>(hist, lossacc, beta, out);
}